// Round 4
// baseline (156.855 us; speedup 1.0000x reference)
//
#include <hip/hip_runtime.h>
#include <hip/hip_fp16.h>

// GCNRegressor: x[n,128] --GCNConv(W1)--> relu --GCNConv(W2)--> relu --@Wl+bl--> out[n]
// n=100000, E=1600000, IN=128, HID=64.
// R1-R10: CSR+gather, counting sort, fp16 features, MFMA GEMMs: 2913 -> 171 us.
// R11: 8-rows-per-VMEM gather (wave = 8 groups x 8 lanes, uint4/lane): 41.8us agg.
// R12: dot2 + 2-slot loop: VALU cycles -19% but dur +3% -- serialized round-trips.
// R13: dot2 + branchy slot-skip: VALU cycles -25%, dur +15%. LESSON: agg is
//      LATENCY-bound; VALUBusy was overlapped work hiding the dependent chain.
// R14: 2 nodes per wave, software-pipelined (16 VMEM in flight): 162 -> 148.7.
// R15: fixed 32-slot colidx (cfix[node*32+slot], dummy offsets baked in at CSR
//      build). Removes the rowptr->colidx dependency (chain 3 -> 2 levels) and
//      ALL main-path masking VALU; colidx addresses are pure arithmetic, so the
//      pipeline deepens to 4 nodes/wave (32 VMEM in flight) for free. deg>32
//      handled via small per-bucket overflow array (rowptr off critical path).

#define SHIFT 9
#define BSZ   (1 << SHIFT)     // 512 nodes per bucket
#define NBMAX 256
#define BIN_CH 2048
#define BCAP  12288            // per-bucket capacity (mean 8188, 1.5x slack)
#define OCAP  1024             // per-bucket overflow capacity (deg>32 edges; mean ~1)

using f16x8 = __attribute__((ext_vector_type(8))) _Float16;
using f16x2 = __attribute__((ext_vector_type(2))) _Float16;
using f32x4 = __attribute__((ext_vector_type(4))) float;

// ---- Phase 1: bin edges into fixed-capacity buckets; bcursor = counts ----
// pack src(17b) | local_node(9b)<<17. Block 0 also zeroes the dummy hs row.
__global__ __launch_bounds__(256) void k_bin(const int* __restrict__ src,
                                             const int* __restrict__ dst,
                                             int* __restrict__ bcursor,
                                             unsigned* __restrict__ binned,
                                             __half* __restrict__ hs, int n, int E) {
    if (blockIdx.x == 0 && threadIdx.x < 8) {
        uint4 z = {0u, 0u, 0u, 0u};
        reinterpret_cast<uint4*>(hs + ((size_t)n << 6))[threadIdx.x] = z;
    }
    __shared__ int h[NBMAX];
    __shared__ int base[NBMAX];
    const int beg = blockIdx.x * BIN_CH;
    const int end = min(beg + BIN_CH, E);
    for (int i = threadIdx.x; i < NBMAX; i += 256) h[i] = 0;
    __syncthreads();
    for (int e = beg + threadIdx.x; e < end; e += 256)
        atomicAdd(&h[dst[e] >> SHIFT], 1);
    __syncthreads();
    for (int i = threadIdx.x; i < NBMAX; i += 256) {
        base[i] = h[i] ? atomicAdd(&bcursor[i], h[i]) : 0;
        h[i] = 0;  // reuse as local cursor
    }
    __syncthreads();
    for (int e = beg + threadIdx.x; e < end; e += 256) {
        int d = dst[e];
        int b = d >> SHIFT;
        int off = atomicAdd(&h[b], 1);
        binned[(size_t)b * BCAP + base[b] + off] =
            (unsigned)src[e] | ((unsigned)(d & (BSZ - 1)) << 17);
    }
}

// ---- Phase 2: per-bucket count + overflow scan + fixed-slot placement ----
// cfix[node*32+slot] = src_row_byte_offset, dummy-filled for slot >= deg.
// rowptr[g] = (overflow_base << 8) | min(deg,255); overflow edges (deg>32) go
// to ovf[b*OCAP + obase[j] ...]. No cross-bucket edge prefix needed anymore.
__global__ __launch_bounds__(256) void k_bfill(const unsigned* __restrict__ binned,
                                               const int* __restrict__ counts,
                                               int* __restrict__ rowptr,
                                               int* __restrict__ cfix,
                                               int* __restrict__ ovf,
                                               float* __restrict__ dinv, int n) {
    __shared__ int cnt[BSZ];
    __shared__ int cur[BSZ];
    __shared__ int obase[BSZ];
    __shared__ int stmp[256];
    const int b = blockIdx.x;
    const int t = threadIdx.x;
    const int ecnt = counts[b];
    const unsigned* bp = binned + (size_t)b * BCAP;
    for (int i = t; i < BSZ; i += 256) { cnt[i] = 0; cur[i] = 0; }
    __syncthreads();
    for (int e = t; e < ecnt; e += 256)
        atomicAdd(&cnt[bp[e] >> 17], 1);
    __syncthreads();
    // per-bucket exclusive prefix of overflow amounts max(deg-32,0)
    int v0 = max(cnt[2 * t] - 32, 0), v1 = max(cnt[2 * t + 1] - 32, 0);
    int s = v0 + v1;
    stmp[t] = s;
    __syncthreads();
    for (int off = 1; off < 256; off <<= 1) {
        int u = (t >= off) ? stmp[t - off] : 0;
        __syncthreads();
        stmp[t] += u;
        __syncthreads();
    }
    int ex = stmp[t] - s;
    obase[2 * t] = ex;
    obase[2 * t + 1] = ex + v0;
    __syncthreads();
    const int gbase = b << SHIFT;
    const int dum = (int)((unsigned)n << 7);
    // rowptr + dinv
    for (int j = t; j < BSZ; j += 256) {
        int g = gbase + j;
        if (g < n) {
            int dg = cnt[j];
            rowptr[g] = (int)(((unsigned)(b * OCAP + obase[j]) << 8) |
                              (unsigned)min(dg, 255));
            dinv[g] = rsqrtf((float)dg + 1.0f);
        }
    }
    // dummy prefill for slots >= deg (disjoint from placement's slots < deg)
    for (int sx = t; sx < BSZ * 32; sx += 256) {
        int j = sx >> 5, slot = sx & 31;
        int g = gbase + j;
        if (g < n && slot >= cnt[j]) cfix[(size_t)g * 32 + slot] = dum;
    }
    // placement
    for (int e = t; e < ecnt; e += 256) {
        unsigned pv = bp[e];
        int j = pv >> 17;
        int off = atomicAdd(&cur[j], 1);
        int so = (int)((pv & 0x1FFFFu) << 7);  // byte offset of src row
        if (off < 32) cfix[(size_t)(gbase + j) * 32 + off] = so;
        else          ovf[b * OCAP + obase[j] + off - 32] = so;
    }
}

// MFMA GEMM: C16[n,64] = fp16( (A[n,K] @ W[K,64]) * dinv[row] ).
// Block = 256 threads = 4 waves; wave w computes rows rb+w*16..+15, all 64 cols.
template <int K, bool A_FP32>
__global__ __launch_bounds__(256) void k_gemm_mfma(const void* __restrict__ Av,
                                                   const float* __restrict__ W,
                                                   const float* __restrict__ dinv,
                                                   __half* __restrict__ C, int n) {
    constexpr int KP = K + 8;  // padded LDS row stride in halves (16B aligned)
    __shared__ _Float16 Wt[64 * KP];
    const int tid = threadIdx.x;
    for (int i = tid; i < K * 64; i += 256) {
        int k = i >> 6, c = i & 63;
        Wt[c * KP + k] = (_Float16)W[i];
    }
    __syncthreads();

    const int lane = tid & 63;
    const int wv = tid >> 6;
    const int r16 = lane & 15;
    const int kq = lane >> 4;                       // 0..3
    const int rb = blockIdx.x * 64 + wv * 16;
    const int arow = min(rb + r16, n - 1);          // clamped A row for this lane

    f32x4 acc[4] = {{0.f,0.f,0.f,0.f},{0.f,0.f,0.f,0.f},
                    {0.f,0.f,0.f,0.f},{0.f,0.f,0.f,0.f}};

#pragma unroll
    for (int kk = 0; kk < K; kk += 32) {
        f16x8 a;
        if (A_FP32) {
            const float* Ap = (const float*)Av + (size_t)arow * K + kk + kq * 8;
            float4 f0 = *reinterpret_cast<const float4*>(Ap);
            float4 f1 = *reinterpret_cast<const float4*>(Ap + 4);
            a[0] = (_Float16)f0.x; a[1] = (_Float16)f0.y;
            a[2] = (_Float16)f0.z; a[3] = (_Float16)f0.w;
            a[4] = (_Float16)f1.x; a[5] = (_Float16)f1.y;
            a[6] = (_Float16)f1.z; a[7] = (_Float16)f1.w;
        } else {
            const _Float16* Ap = (const _Float16*)Av + (size_t)arow * K + kk + kq * 8;
            a = *reinterpret_cast<const f16x8*>(Ap);
        }
#pragma unroll
        for (int nt = 0; nt < 4; ++nt) {
            f16x8 b = *reinterpret_cast<const f16x8*>(&Wt[(nt * 16 + r16) * KP + kk + kq * 8]);
            acc[nt] = __builtin_amdgcn_mfma_f32_16x16x32_f16(a, b, acc[nt], 0, 0, 0);
        }
    }

#pragma unroll
    for (int r = 0; r < 4; ++r) {
        const int row = rb + kq * 4 + r;
        if (row < n) {
            const float di = dinv[row];
#pragma unroll
            for (int nt = 0; nt < 4; ++nt)
                C[((size_t)row << 6) + nt * 16 + r16] = __float2half(acc[nt][r] * di);
        }
    }
}

// Accumulate 8 fp16 (one uint4) into acc[8] via v_dot2_f32_f16: one VALU op per
// value (convert+add fused, fp32 accumulate). Masks (1,0)/(0,1) keep channels
// separate; exact 1.0-multiply => bit-identical to cvt+add.
__device__ __forceinline__ void dotu4(float acc[8], uint4 u, f16x2 pl, f16x2 ph) {
    union { uint4 u4; f16x2 h[4]; } v;
    v.u4 = u;
    acc[0] = __builtin_amdgcn_fdot2(v.h[0], pl, acc[0], false);
    acc[1] = __builtin_amdgcn_fdot2(v.h[0], ph, acc[1], false);
    acc[2] = __builtin_amdgcn_fdot2(v.h[1], pl, acc[2], false);
    acc[3] = __builtin_amdgcn_fdot2(v.h[1], ph, acc[3], false);
    acc[4] = __builtin_amdgcn_fdot2(v.h[2], pl, acc[4], false);
    acc[5] = __builtin_amdgcn_fdot2(v.h[2], ph, acc[5], false);
    acc[6] = __builtin_amdgcn_fdot2(v.h[3], pl, acc[6], false);
    acc[7] = __builtin_amdgcn_fdot2(v.h[3], ph, acc[7], false);
}

// Fold partial sums across the 8 groups: after this every lane holds the full
// sums for its channel-slice p.
__device__ __forceinline__ void fold8(float acc[8]) {
#pragma unroll
    for (int m = 8; m <= 32; m <<= 1) {
#pragma unroll
        for (int j = 0; j < 8; ++j)
            acc[j] += __shfl_xor(acc[j], m, 64);
    }
}

// Rare tail (deg > 32, wave-uniform): overflow edges 32..deg-1 live at
// ovf[obeg + edge - 32]; masked to the dummy row past deg.
__device__ __forceinline__ void tail_node(const char* __restrict__ hsb,
                                          const int* __restrict__ ovf,
                                          unsigned pk, int g, int p,
                                          unsigned dum, float acc[8],
                                          f16x2 pl, f16x2 ph) {
    const int deg = (int)(pk & 255u);
    if (deg <= 32) return;                 // wave-uniform
    const int obeg = (int)(pk >> 8);
    const int t = deg - g;                 // slot k valid iff 8*k < t
    const unsigned poff = (unsigned)(p << 4);
    const unsigned dumo = dum + poff;
    const int ns = (deg + 7) >> 3;
    for (int k = 4; k < ns; k += 4) {
        const int ik = obeg + 8 * (k - 4) + g;
        unsigned c0 = (unsigned)ovf[ik]      + poff;   // slack past end is safe
        unsigned c1 = (unsigned)ovf[ik + 8]  + poff;
        unsigned c2 = (unsigned)ovf[ik + 16] + poff;
        unsigned c3 = (unsigned)ovf[ik + 24] + poff;
        const int kb = 8 * k;
        uint4 u0 = *reinterpret_cast<const uint4*>(hsb + ((kb      < t) ? c0 : dumo));
        uint4 u1 = *reinterpret_cast<const uint4*>(hsb + ((kb + 8  < t) ? c1 : dumo));
        uint4 u2 = *reinterpret_cast<const uint4*>(hsb + ((kb + 16 < t) ? c2 : dumo));
        uint4 u3 = *reinterpret_cast<const uint4*>(hsb + ((kb + 24 < t) ? c3 : dumo));
        dotu4(acc, u0, pl, ph);
        dotu4(acc, u1, pl, ph);
        dotu4(acc, u2, pl, ph);
        dotu4(acc, u3, pl, ph);
    }
}

// 4-node pipelined gather. Wave = 8 groups x 8 lanes; each group's uint4 load
// fetches one full 128B row. cfix addresses are pure arithmetic (no rowptr
// dependency): ALL 16 colidx loads then ALL 16 gather uint4s issue
// back-to-back (32 VMEM in flight). No masking in the main path -- dummy
// offsets are baked into cfix. Tails only for deg>32 (~0.02% of nodes).
__device__ __forceinline__ void gather_quad(const char* __restrict__ hsb,
                                            const int* __restrict__ cfix,
                                            const int* __restrict__ ovf,
                                            int ic0, int ic1, int ic2, int ic3,
                                            unsigned pk0, unsigned pk1,
                                            unsigned pk2, unsigned pk3,
                                            int g, int p, unsigned dum,
                                            float a0[8], float a1[8],
                                            float a2[8], float a3[8]) {
    const f16x2 pl = {(_Float16)1.0f, (_Float16)0.0f};
    const f16x2 ph = {(_Float16)0.0f, (_Float16)1.0f};
    const unsigned poff = (unsigned)(p << 4);
    const int b0 = ic0 * 32 + g;
    const int b1 = ic1 * 32 + g;
    const int b2 = ic2 * 32 + g;
    const int b3 = ic3 * 32 + g;
    // --- 16 colidx loads (addresses known at wave start) ---
    unsigned oa0 = (unsigned)cfix[b0]      + poff;
    unsigned oa1 = (unsigned)cfix[b0 + 8]  + poff;
    unsigned oa2 = (unsigned)cfix[b0 + 16] + poff;
    unsigned oa3 = (unsigned)cfix[b0 + 24] + poff;
    unsigned ob0 = (unsigned)cfix[b1]      + poff;
    unsigned ob1 = (unsigned)cfix[b1 + 8]  + poff;
    unsigned ob2 = (unsigned)cfix[b1 + 16] + poff;
    unsigned ob3 = (unsigned)cfix[b1 + 24] + poff;
    unsigned oc0 = (unsigned)cfix[b2]      + poff;
    unsigned oc1 = (unsigned)cfix[b2 + 8]  + poff;
    unsigned oc2 = (unsigned)cfix[b2 + 16] + poff;
    unsigned oc3 = (unsigned)cfix[b2 + 24] + poff;
    unsigned od0 = (unsigned)cfix[b3]      + poff;
    unsigned od1 = (unsigned)cfix[b3 + 8]  + poff;
    unsigned od2 = (unsigned)cfix[b3 + 16] + poff;
    unsigned od3 = (unsigned)cfix[b3 + 24] + poff;
    // --- 16 gathers ---
    uint4 ua0 = *reinterpret_cast<const uint4*>(hsb + oa0);
    uint4 ua1 = *reinterpret_cast<const uint4*>(hsb + oa1);
    uint4 ua2 = *reinterpret_cast<const uint4*>(hsb + oa2);
    uint4 ua3 = *reinterpret_cast<const uint4*>(hsb + oa3);
    uint4 ub0 = *reinterpret_cast<const uint4*>(hsb + ob0);
    uint4 ub1 = *reinterpret_cast<const uint4*>(hsb + ob1);
    uint4 ub2 = *reinterpret_cast<const uint4*>(hsb + ob2);
    uint4 ub3 = *reinterpret_cast<const uint4*>(hsb + ob3);
    uint4 uc0 = *reinterpret_cast<const uint4*>(hsb + oc0);
    uint4 uc1 = *reinterpret_cast<const uint4*>(hsb + oc1);
    uint4 uc2 = *reinterpret_cast<const uint4*>(hsb + oc2);
    uint4 uc3 = *reinterpret_cast<const uint4*>(hsb + oc3);
    uint4 ud0 = *reinterpret_cast<const uint4*>(hsb + od0);
    uint4 ud1 = *reinterpret_cast<const uint4*>(hsb + od1);
    uint4 ud2 = *reinterpret_cast<const uint4*>(hsb + od2);
    uint4 ud3 = *reinterpret_cast<const uint4*>(hsb + od3);
    // --- consume in order; later nodes' loads still in flight ---
    dotu4(a0, ua0, pl, ph);
    dotu4(a0, ua1, pl, ph);
    dotu4(a0, ua2, pl, ph);
    dotu4(a0, ua3, pl, ph);
    dotu4(a1, ub0, pl, ph);
    dotu4(a1, ub1, pl, ph);
    dotu4(a1, ub2, pl, ph);
    dotu4(a1, ub3, pl, ph);
    dotu4(a2, uc0, pl, ph);
    dotu4(a2, uc1, pl, ph);
    dotu4(a2, uc2, pl, ph);
    dotu4(a2, uc3, pl, ph);
    dotu4(a3, ud0, pl, ph);
    dotu4(a3, ud1, pl, ph);
    dotu4(a3, ud2, pl, ph);
    dotu4(a3, ud3, pl, ph);
    // --- rare tails ---
    tail_node(hsb, ovf, pk0, g, p, dum, a0, pl, ph);
    tail_node(hsb, ovf, pk1, g, p, dum, a1, pl, ph);
    tail_node(hsb, ovf, pk2, g, p, dum, a2, pl, ph);
    tail_node(hsb, ovf, pk3, g, p, dum, a3, pl, ph);
    fold8(a0);
    fold8(a1);
    fold8(a2);
    fold8(a3);
}

// Select this lane's node accumulator (nsel in 0..3) -- 16 cndmasks, once/wave.
__device__ __forceinline__ void sel4(float a[8], int nsel, const float a0[8],
                                     const float a1[8], const float a2[8],
                                     const float a3[8]) {
#pragma unroll
    for (int j = 0; j < 8; ++j) {
        float x01 = (nsel & 1) ? a1[j] : a0[j];
        float x23 = (nsel & 1) ? a3[j] : a2[j];
        a[j] = (nsel & 2) ? x23 : x01;
    }
}

// conv1 aggregation: out16 = fp16(relu(di*(sum_e hs[src_e] + hs_i) + b)).
// 4 nodes per wave; epilogue: lane group g (g<4) finalizes node i0+g.
__global__ __launch_bounds__(256) void k_agg_relu(const __half* __restrict__ hs,
                                                  const int* __restrict__ rowptr,
                                                  const int* __restrict__ cfix,
                                                  const int* __restrict__ ovf,
                                                  const float* __restrict__ dinv,
                                                  const float* __restrict__ b,
                                                  __half* __restrict__ out, int n) {
    const int wv = threadIdx.x >> 6;
    const int i0 = blockIdx.x * 16 + wv * 4;
    const int lane = threadIdx.x & 63;
    if (i0 >= n) return;
    const int g = lane >> 3, p = lane & 7;
    const int ic0 = i0;
    const int ic1 = min(i0 + 1, n - 1);
    const int ic2 = min(i0 + 2, n - 1);
    const int ic3 = min(i0 + 3, n - 1);
    const int nsel = g & 3;
    const int it = i0 + nsel;              // unclamped, for store guard
    const int iw = min(it, n - 1);
    // independent loads, hoisted (off critical path)
    const unsigned pk0 = (unsigned)rowptr[ic0];
    const unsigned pk1 = (unsigned)rowptr[ic1];
    const unsigned pk2 = (unsigned)rowptr[ic2];
    const unsigned pk3 = (unsigned)rowptr[ic3];
    uint4 su = *reinterpret_cast<const uint4*>(hs + ((size_t)iw << 6) + (p << 3));
    const float di = dinv[iw];
    float a0[8] = {}, a1[8] = {}, a2[8] = {}, a3[8] = {};
    gather_quad((const char*)hs, cfix, ovf, ic0, ic1, ic2, ic3,
                pk0, pk1, pk2, pk3, g, p, (unsigned)n << 7, a0, a1, a2, a3);
    if (lane < 32 && it < n) {
        const f16x2 pl = {(_Float16)1.0f, (_Float16)0.0f};
        const f16x2 ph = {(_Float16)0.0f, (_Float16)1.0f};
        float a[8];
        sel4(a, nsel, a0, a1, a2, a3);
        dotu4(a, su, pl, ph);
        float4 b0 = *reinterpret_cast<const float4*>(b + (p << 3));
        float4 b1 = *reinterpret_cast<const float4*>(b + (p << 3) + 4);
        __half2 h0 = __halves2half2(__float2half(fmaxf(fmaf(a[0], di, b0.x), 0.f)),
                                    __float2half(fmaxf(fmaf(a[1], di, b0.y), 0.f)));
        __half2 h1 = __halves2half2(__float2half(fmaxf(fmaf(a[2], di, b0.z), 0.f)),
                                    __float2half(fmaxf(fmaf(a[3], di, b0.w), 0.f)));
        __half2 h2 = __halves2half2(__float2half(fmaxf(fmaf(a[4], di, b1.x), 0.f)),
                                    __float2half(fmaxf(fmaf(a[5], di, b1.y), 0.f)));
        __half2 h3 = __halves2half2(__float2half(fmaxf(fmaf(a[6], di, b1.z), 0.f)),
                                    __float2half(fmaxf(fmaf(a[7], di, b1.w), 0.f)));
        uint4 u;
        u.x = *reinterpret_cast<unsigned*>(&h0);
        u.y = *reinterpret_cast<unsigned*>(&h1);
        u.z = *reinterpret_cast<unsigned*>(&h2);
        u.w = *reinterpret_cast<unsigned*>(&h3);
        *reinterpret_cast<uint4*>(out + ((size_t)it << 6) + (p << 3)) = u;
    }
}

// conv2 aggregation + relu + (.@Wl + bl) head, fused. 4 nodes per wave;
// group g handles node i0+(g&3) (groups 4-7 redundant); xor-1,2,4 reduce stays
// within each 8-lane group; lane g*8 of groups 0-3 stores node i0+g.
__global__ __launch_bounds__(256) void k_agg_head(const __half* __restrict__ hs,
                                                  const int* __restrict__ rowptr,
                                                  const int* __restrict__ cfix,
                                                  const int* __restrict__ ovf,
                                                  const float* __restrict__ dinv,
                                                  const float* __restrict__ b2,
                                                  const float* __restrict__ Wl,
                                                  const float* __restrict__ bl,
                                                  float* __restrict__ out, int n) {
    const int wv = threadIdx.x >> 6;
    const int i0 = blockIdx.x * 16 + wv * 4;
    const int lane = threadIdx.x & 63;
    if (i0 >= n) return;
    const int g = lane >> 3, p = lane & 7;
    const int ic0 = i0;
    const int ic1 = min(i0 + 1, n - 1);
    const int ic2 = min(i0 + 2, n - 1);
    const int ic3 = min(i0 + 3, n - 1);
    const int nsel = g & 3;
    const int it = i0 + nsel;
    const int iw = min(it, n - 1);
    const unsigned pk0 = (unsigned)rowptr[ic0];
    const unsigned pk1 = (unsigned)rowptr[ic1];
    const unsigned pk2 = (unsigned)rowptr[ic2];
    const unsigned pk3 = (unsigned)rowptr[ic3];
    uint4 su = *reinterpret_cast<const uint4*>(hs + ((size_t)iw << 6) + (p << 3));
    const float di = dinv[iw];
    float a0[8] = {}, a1[8] = {}, a2[8] = {}, a3[8] = {};
    gather_quad((const char*)hs, cfix, ovf, ic0, ic1, ic2, ic3,
                pk0, pk1, pk2, pk3, g, p, (unsigned)n << 7, a0, a1, a2, a3);
    const f16x2 pl = {(_Float16)1.0f, (_Float16)0.0f};
    const f16x2 ph = {(_Float16)0.0f, (_Float16)1.0f};
    float a[8];
    sel4(a, nsel, a0, a1, a2, a3);
    dotu4(a, su, pl, ph);
    float4 b0 = *reinterpret_cast<const float4*>(b2 + (p << 3));
    float4 b1 = *reinterpret_cast<const float4*>(b2 + (p << 3) + 4);
    float4 w0 = *reinterpret_cast<const float4*>(Wl + (p << 3));
    float4 w1 = *reinterpret_cast<const float4*>(Wl + (p << 3) + 4);
    float v = fmaxf(fmaf(a[0], di, b0.x), 0.f) * w0.x
            + fmaxf(fmaf(a[1], di, b0.y), 0.f) * w0.y
            + fmaxf(fmaf(a[2], di, b0.z), 0.f) * w0.z
            + fmaxf(fmaf(a[3], di, b0.w), 0.f) * w0.w
            + fmaxf(fmaf(a[4], di, b1.x), 0.f) * w1.x
            + fmaxf(fmaf(a[5], di, b1.y), 0.f) * w1.y
            + fmaxf(fmaf(a[6], di, b1.z), 0.f) * w1.z
            + fmaxf(fmaf(a[7], di, b1.w), 0.f) * w1.w;
    v += __shfl_xor(v, 1, 64);
    v += __shfl_xor(v, 2, 64);
    v += __shfl_xor(v, 4, 64);
    if (p == 0 && g < 4 && it < n) out[it] = v + bl[0];
}

extern "C" void kernel_launch(void* const* d_in, const int* in_sizes, int n_in,
                              void* d_out, int out_size, void* d_ws, size_t ws_size,
                              hipStream_t stream) {
    const float* x  = (const float*)d_in[0];
    const int*   ei = (const int*)d_in[1];
    const float* W1 = (const float*)d_in[2];
    const float* b1 = (const float*)d_in[3];
    const float* W2 = (const float*)d_in[4];
    const float* b2 = (const float*)d_in[5];
    const float* Wl = (const float*)d_in[6];
    const float* bl = (const float*)d_in[7];
    float* out = (float*)d_out;

    const int n = in_sizes[0] / 128;   // 100000
    const int E = in_sizes[1] / 2;     // 1600000
    const int* src = ei;
    const int* dst = ei + E;
    const int nb = (n + BSZ - 1) >> SHIFT;  // 196

    char* ws = (char*)d_ws;
    size_t o = 0;
    auto alloc = [&](size_t bytes) {
        void* p = ws + o;
        o = (o + bytes + 255) & ~(size_t)255;
        return p;
    };
    float* dinv    = (float*)alloc((size_t)n * 4);
    int*   bcursor = (int*)  alloc((size_t)NBMAX * 4);
    int*   rowptr  = (int*)  alloc((size_t)(n + 1) * 4);
    int*   cfix    = (int*)  alloc((size_t)n * 32 * 4);          // fixed 32-slot colidx
    int*   ovf     = (int*)  alloc(((size_t)nb * OCAP + 64) * 4);// deg>32 overflow
    __half* hs     = (__half*)alloc((size_t)(n + 1) * 64 * 2);   // +1 zeroed dummy row
    __half* bufA   = (__half*)alloc((size_t)n * 64 * 2);         // fp16 relu output
    unsigned* binned = (unsigned*)alloc((size_t)nb * BCAP * 4);  // bucketed edges

    // ---- CSR build (fixed-capacity counting sort; no pre-histogram) ----
    hipMemsetAsync(bcursor, 0, NBMAX * sizeof(int), stream);
    k_bin<<<(E + BIN_CH - 1) / BIN_CH, 256, 0, stream>>>(src, dst, bcursor, binned,
                                                         hs, n, E);
    k_bfill<<<nb, 256, 0, stream>>>(binned, bcursor, rowptr, cfix, ovf, dinv, n);

    // ---- conv1 ----
    k_gemm_mfma<128, true><<<(n + 63) / 64, 256, 0, stream>>>(x, W1, dinv, hs, n);
    k_agg_relu<<<(n + 15) / 16, 256, 0, stream>>>(hs, rowptr, cfix, ovf, dinv, b1,
                                                  bufA, n);

    // ---- conv2 + head ----
    k_gemm_mfma<64, false><<<(n + 63) / 64, 256, 0, stream>>>(bufA, W2, dinv, hs, n);
    k_agg_head<<<(n + 15) / 16, 256, 0, stream>>>(hs, rowptr, cfix, ovf, dinv, b2,
                                                  Wl, bl, out, n);
}